// Round 8
// baseline (545.109 us; speedup 1.0000x reference)
//
#include <hip/hip_runtime.h>

// SOHMM forward, MI355X gfx950 — round 8: one block per j (128 x 1024), tag-in-data y,
// pipelined arrival-gated M. Same protocol as round 7 (passing):
//  - y words in d_out carry tag 2s+1 in the f32 low byte (deterministic rounding);
//    consumers poll y directly -> one LLC trip per step.
//  - stabilizer for step s = M_{s-2}; swept arrival-gated at END of step s-1 where it
//    is already resident (zero expected wait). mslot[s&7][prod][b] = (tag<<24)|mono24,
//    tag = s+1. d_ws memset(0) per launch re-arms gates each graph replay.
// Round-8 deltas: ih-split removed (halves rendezvous width, y-poll traffic, staging
// exp work); 2 output tiles per wave; M sweep = 8 producers/thread.

#define Hd 128
#define Bd 64
#define Sd 128
#define Vd 32000
#define HBc (Hd * Bd)          // 8192
#define HHBc (Hd * Hd * Bd)    // 1048576
#define NBLK 128
#define NTHR 1024
#define EPSF 1e-12f
#define FTAG 200u
#define SLOTW ((size_t)NBLK * Bd)   // words per M slot = 8192

typedef __attribute__((ext_vector_type(4))) float f32x4;
typedef __attribute__((ext_vector_type(8))) short s16x8;
typedef __attribute__((ext_vector_type(4))) short s16x4;

__device__ __forceinline__ short f2bf(float f) {
  unsigned u = __builtin_bit_cast(unsigned, f);
  unsigned r = (u + 0x7fffu + ((u >> 16) & 1u)) >> 16;
  return (short)(r & 0xffffu);
}

// Monotone total-order f32 <-> u32.
__device__ __forceinline__ unsigned mono_enc(float f) {
  unsigned u = __builtin_bit_cast(unsigned, f);
  return u ^ ((u & 0x80000000u) ? 0xFFFFFFFFu : 0x80000000u);
}
__device__ __forceinline__ float mono_dec(unsigned m) {
  unsigned u = (m & 0x80000000u) ? (m ^ 0x80000000u) : ~m;
  return __builtin_bit_cast(float, u);
}
__device__ __forceinline__ unsigned packM(float f, unsigned tag) {
  return (tag << 24) | (mono_enc(f) >> 8);
}
__device__ __forceinline__ float decM(unsigned w) {
  return mono_dec((w & 0x00FFFFFFu) << 8);
}
__device__ __forceinline__ unsigned pack_y(float v, unsigned tag) {
  unsigned u = __builtin_bit_cast(unsigned, v);
  return ((u + 0x80u) & 0xFFFFFF00u) | tag;
}
__device__ __forceinline__ float as_f(unsigned u) { return __builtin_bit_cast(float, u); }
__device__ __forceinline__ unsigned pack24(float f, unsigned tag) {
  unsigned u = __builtin_bit_cast(unsigned, f);
  return ((u + 0x80u) & 0xFFFFFF00u) | tag;
}
__device__ __forceinline__ float dec24(unsigned v) {
  return __builtin_bit_cast(float, v & 0xFFFFFF00u);
}

// LLC-coherent accessors (agent scope -> sc1 both directions).
__device__ __forceinline__ unsigned ld_u32(const unsigned* p) {
  return __hip_atomic_load(p, __ATOMIC_RELAXED, __HIP_MEMORY_SCOPE_AGENT);
}
__device__ __forceinline__ void st_u32(unsigned* p, unsigned v) {
  __hip_atomic_store(p, v, __ATOMIC_RELAXED, __HIP_MEMORY_SCOPE_AGENT);
}

__global__ __launch_bounds__(NTHR) void sohmm_persistent(
    const int* __restrict__ ids, const float* __restrict__ alpha,
    const float* __restrict__ beta, const float* __restrict__ gamma,
    float* __restrict__ out, unsigned* __restrict__ mslot,
    unsigned* __restrict__ fpart) {
  const int tid = threadIdx.x;
  const int bid = blockIdx.x;      // = j
  const int j = bid;
  const int lane = tid & 63;
  const int w = tid >> 6;          // wave 0..15
  const int l15 = lane & 15;
  const int g4 = lane >> 4;
  const int it = w & 7;            // i-tile 0..7
  const int bh = w >> 3;           // b-half 0..1
  const int i0 = it * 16;
  const int b0 = bh * 32 + l15;    // acc0's b
  const int b1 = b0 + 16;          // acc1's b
  const int sb = tid & 63;         // staging/sweep b
  const int sq = tid >> 6;         // staging k-group / sweep producer group

  __shared__ __align__(16) short ET[64][132];     // E^T[b][k] bf16 (stride 264 B)
  __shared__ __align__(16) float ip_all[Sd][Bd];  // beta[j, ids[b, S-1-t]]
  __shared__ unsigned redS[16][64];
  __shared__ float redF[16][64];
  __shared__ float wred[8][64];
  __shared__ float gex[128];
  __shared__ float MbS[64];        // stabilizer per b (M_{s-2} at step s)

  // ---- A fragments: alpha[i, j, :] for this wave's i-tile ----
  s16x8 afrag[4];
  {
    const int i = i0 + l15;
    const float* ap = alpha + ((size_t)i * Hd + j) * Hd;
#pragma unroll
    for (int kc = 0; kc < 4; ++kc) {
      const int k = kc * 32 + g4 * 8;
      f32x4 a0 = *(const f32x4*)(ap + k);
      f32x4 a1 = *(const f32x4*)(ap + k + 4);
      s16x8 f;
      f[0] = f2bf(a0[0]); f[1] = f2bf(a0[1]); f[2] = f2bf(a0[2]); f[3] = f2bf(a0[3]);
      f[4] = f2bf(a1[0]); f[5] = f2bf(a1[1]); f[6] = f2bf(a1[2]); f[7] = f2bf(a1[3]);
      afrag[kc] = f;
    }
  }

  // ---- phase 0: ip table, gamma stats, tagged y0, publish+sweep M_0 ----
  for (int idx = tid; idx < Sd * Bd; idx += NTHR) {
    const int t = idx >> 6, b = idx & 63;
    ip_all[t][b] = beta[(size_t)j * Vd + ids[b * Sd + (Sd - 1 - t)]];
  }
  {
    float m = -3.4e38f;
#pragma unroll
    for (int c = 0; c < 4; ++c) {
      f32x4 g = *(const f32x4*)(gamma + (size_t)(c * NTHR + tid) * 4);
      m = fmaxf(fmaxf(fmaxf(m, g[0]), g[1]), fmaxf(g[2], g[3]));
    }
#pragma unroll
    for (int o = 32; o >= 1; o >>= 1) m = fmaxf(m, __shfl_xor(m, o, 64));
    if (lane == 0) redF[0][w] = m;
  }
  __syncthreads();  // ip_all + gamma partials visible
  {
    // tagged y0 stores: 128 i-rows x 64 b, 8 words/thread (tag 1)
    const int r = tid >> 3;            // i-row 0..127
    const int bb8 = (tid & 7) * 8;     // b 8-group
    unsigned* yw = (unsigned*)out + ((size_t)r * Hd + j) * Bd + bb8;
#pragma unroll
    for (int e = 0; e < 8; ++e) st_u32(yw + e, pack_y(ip_all[0][bb8 + e], 1u));
  }
  if (tid < 64)
    st_u32(mslot + (size_t)bid * Bd + tid, packM(ip_all[0][tid], 1u));  // M_0, tag 1
  {
    float gm = redF[0][0];
#pragma unroll
    for (int q = 1; q < 16; ++q) gm = fmaxf(gm, redF[0][q]);
    float ss = 0.f;
#pragma unroll
    for (int c = 0; c < 4; ++c) {
      f32x4 g = *(const f32x4*)(gamma + (size_t)(c * NTHR + tid) * 4);
      ss += __expf(g[0] - gm) + __expf(g[1] - gm) + __expf(g[2] - gm) + __expf(g[3] - gm);
    }
#pragma unroll
    for (int o = 32; o >= 1; o >>= 1) ss += __shfl_xor(ss, o, 64);
    if (lane == 0) redF[1][w] = ss;
    __syncthreads();
    float gs = 0.f;
#pragma unroll
    for (int q = 0; q < 16; ++q) gs += redF[1][q];
    if (tid < 128) gex[tid] = __expf(gamma[(size_t)tid * Hd + j] - gm) * (1.f / gs);
  }
  // sweep M_0 (tag 1): 8 producers per thread
  {
    const unsigned tg = 1u;
    const unsigned* pm = mslot + (size_t)(sq * 8) * Bd + sb;
    unsigned g[8];
#pragma unroll
    for (int q = 0; q < 8; ++q) g[q] = ld_u32(pm + (size_t)q * Bd);
    unsigned spins = 0;
    for (;;) {
      unsigned bad = 0;
#pragma unroll
      for (int q = 0; q < 8; ++q) bad |= (g[q] >> 24) ^ tg;
      if (!bad) break;
      if (++spins > (1u << 18)) break;
      __builtin_amdgcn_s_sleep(1);
#pragma unroll
      for (int q = 0; q < 8; ++q)
        if ((g[q] >> 24) != tg) g[q] = ld_u32(pm + (size_t)q * Bd);
    }
    unsigned mx = 0u;
#pragma unroll
    for (int q = 0; q < 8; ++q) mx = g[q] > mx ? g[q] : mx;
    redS[sq][sb] = mx;
  }
  __syncthreads();
  if (tid < 64) {
    unsigned mx = 0u;
#pragma unroll
    for (int q = 0; q < 16; ++q) mx = redS[q][tid] > mx ? redS[q][tid] : mx;
    MbS[tid] = decM(mx);
  }
  __syncthreads();

  // ---- main scan: s = 1 .. 127 ----
  float val0[4], val1[4];
#pragma unroll 1
  for (int s = 1; s < Sd; ++s) {
    const unsigned ytag = (unsigned)(2 * s - 1);   // tag of y_{s-1}
    const unsigned wtag = (unsigned)(2 * s + 1);   // tag on y_s

    // 1) poll this thread's 8 y_{s-1} words (k = sq*8.., b = sb)
    const int k0 = sq * 8;
    const unsigned* ypw = (const unsigned*)out + (size_t)(s - 1) * HHBc + (size_t)j * HBc + sb;
    unsigned g[8];
#pragma unroll
    for (int e = 0; e < 8; ++e) g[e] = ld_u32(ypw + (size_t)(k0 + e) * Bd);
    {
      unsigned spins = 0;
      for (;;) {
        unsigned bad = 0;
#pragma unroll
        for (int e = 0; e < 8; ++e) bad |= (g[e] & 0xFFu) ^ ytag;
        if (!bad) break;
        if (++spins > (1u << 18)) break;
        __builtin_amdgcn_s_sleep(1);
#pragma unroll
        for (int e = 0; e < 8; ++e)
          if ((g[e] & 0xFFu) != ytag) g[e] = ld_u32(ypw + (size_t)(k0 + e) * Bd);
      }
    }

    // 2) E = exp(y - M_{s-2}) -> bf16 -> ET (arg <= ~small; clamp is safety)
    {
      const float Mv = MbS[sb];
      union { s16x8 v; } u;
#pragma unroll
      for (int e = 0; e < 8; ++e)
        ((short*)&u.v)[e] = f2bf(__expf(fminf(as_f(g[e]) - Mv, 1.0f)));
      *(s16x8*)&ET[sb][k0] = u.v;
    }
    __syncthreads();

    // 3) MFMA: two 16x16 tiles per wave (same i-tile, adjacent b-tiles)
    f32x4 acc0 = (f32x4){0.f, 0.f, 0.f, 0.f};
    f32x4 acc1 = (f32x4){0.f, 0.f, 0.f, 0.f};
#pragma unroll
    for (int kc = 0; kc < 4; ++kc) {
      const int kk = kc * 32 + g4 * 8;
      union { s16x4 h[2]; s16x8 v; } u0, u1;
      u0.h[0] = *(const s16x4*)&ET[b0][kk];
      u0.h[1] = *(const s16x4*)&ET[b0][kk + 4];
      u1.h[0] = *(const s16x4*)&ET[b1][kk];
      u1.h[1] = *(const s16x4*)&ET[b1][kk + 4];
      acc0 = __builtin_amdgcn_mfma_f32_16x16x32_bf16(afrag[kc], u0.v, acc0, 0, 0, 0);
      acc1 = __builtin_amdgcn_mfma_f32_16x16x32_bf16(afrag[kc], u1.v, acc1, 0, 0, 0);
    }

    // 4) epilogue: val = log(acc+eps) + M + ip, tagged y stores, per-b max
    {
      unsigned* ycw = (unsigned*)out + (size_t)s * HHBc;
      const float add0 = MbS[b0] + ip_all[s][b0];
      const float add1 = MbS[b1] + ip_all[s][b1];
      float mx0 = -3.4e38f, mx1 = -3.4e38f;
#pragma unroll
      for (int r = 0; r < 4; ++r) {
        const size_t row = (size_t)(i0 + g4 * 4 + r) * HBc + (size_t)j * Bd;
        float v0 = __logf(acc0[r] + EPSF) + add0;
        float v1 = __logf(acc1[r] + EPSF) + add1;
        val0[r] = v0; val1[r] = v1;
        st_u32(ycw + row + b0, pack_y(v0, wtag));
        st_u32(ycw + row + b1, pack_y(v1, wtag));
        mx0 = fmaxf(mx0, v0);
        mx1 = fmaxf(mx1, v1);
      }
      mx0 = fmaxf(mx0, __shfl_xor(mx0, 16, 64));
      mx0 = fmaxf(mx0, __shfl_xor(mx0, 32, 64));
      mx1 = fmaxf(mx1, __shfl_xor(mx1, 16, 64));
      mx1 = fmaxf(mx1, __shfl_xor(mx1, 32, 64));
      if (lane < 16) {
        wred[it][bh * 32 + lane] = mx0;
        wred[it][bh * 32 + 16 + lane] = mx1;
      }
    }
    __syncthreads();
    // publish M_s (tag s+1, slot s&7)
    if (tid < 64) {
      float m = wred[0][tid];
#pragma unroll
      for (int q = 1; q < 8; ++q) m = fmaxf(m, wred[q][tid]);
      st_u32(mslot + (size_t)(s & 7) * SLOTW + (size_t)bid * Bd + tid,
             packM(m, (unsigned)s + 1u));
    }
    // tail sweep for next step's stabilizer: tag tg = max(1,s) -> M_{tg-1}
    {
      const unsigned tg = (s >= 2) ? (unsigned)s : 1u;
      const unsigned* pm = mslot + (size_t)((tg - 1u) & 7u) * SLOTW + (size_t)(sq * 8) * Bd + sb;
      unsigned g2[8];
#pragma unroll
      for (int q = 0; q < 8; ++q) g2[q] = ld_u32(pm + (size_t)q * Bd);
      unsigned spins = 0;
      for (;;) {
        unsigned bad = 0;
#pragma unroll
        for (int q = 0; q < 8; ++q) bad |= (g2[q] >> 24) ^ tg;
        if (!bad) break;
        if (++spins > (1u << 18)) break;
        __builtin_amdgcn_s_sleep(1);
#pragma unroll
        for (int q = 0; q < 8; ++q)
          if ((g2[q] >> 24) != tg) g2[q] = ld_u32(pm + (size_t)q * Bd);
      }
      unsigned mx = 0u;
#pragma unroll
      for (int q = 0; q < 8; ++q) mx = g2[q] > mx ? g2[q] : mx;
      redS[sq][sb] = mx;
    }
    __syncthreads();
    if (tid < 64) {
      unsigned mx = 0u;
#pragma unroll
      for (int q = 0; q < 16; ++q) mx = redS[q][tid] > mx ? redS[q][tid] : mx;
      MbS[tid] = decM(mx);
    }
    __syncthreads();
  }

  // ---- final: y_final[b] = log(sum_ij gamma_exp*exp(y_127 - M) + eps) + M ----
  // MbS = M_126; val <= M_127 <= M_126 -> arg <= 0.
  {
    float s0 = 0.f, s1 = 0.f;
#pragma unroll
    for (int r = 0; r < 4; ++r) {
      const float gx = gex[i0 + g4 * 4 + r];
      s0 += gx * __expf(fminf(val0[r] - MbS[b0], 1.0f));
      s1 += gx * __expf(fminf(val1[r] - MbS[b1], 1.0f));
    }
    s0 += __shfl_xor(s0, 16, 64);
    s0 += __shfl_xor(s0, 32, 64);
    s1 += __shfl_xor(s1, 16, 64);
    s1 += __shfl_xor(s1, 32, 64);
    if (lane < 16) {
      wred[it][bh * 32 + lane] = s0;
      wred[it][bh * 32 + 16 + lane] = s1;
    }
  }
  __syncthreads();
  if (tid < 64) {
    float sm = wred[0][tid];
#pragma unroll
    for (int q = 1; q < 8; ++q) sm += wred[q][tid];
    st_u32(fpart + (size_t)bid * Bd + tid, pack24(sm, FTAG));
  }

  if (bid == 0) {
    const unsigned* pm = fpart + (size_t)(sq * 8) * Bd + sb;
    unsigned g[8];
#pragma unroll
    for (int q = 0; q < 8; ++q) g[q] = ld_u32(pm + (size_t)q * Bd);
    {
      unsigned spins = 0;
      for (;;) {
        unsigned bad = 0;
#pragma unroll
        for (int q = 0; q < 8; ++q) bad |= (g[q] & 0xFFu) ^ FTAG;
        if (!bad) break;
        if (++spins > (1u << 18)) break;
        __builtin_amdgcn_s_sleep(1);
#pragma unroll
        for (int q = 0; q < 8; ++q)
          if ((g[q] & 0xFFu) != FTAG) g[q] = ld_u32(pm + (size_t)q * Bd);
      }
    }
    float s8 = 0.f;
#pragma unroll
    for (int q = 0; q < 8; ++q) s8 += dec24(g[q]);
    redF[sq][sb] = s8;
    __syncthreads();
    if (tid < 64) {
      float tot = 0.f;
#pragma unroll
      for (int q = 0; q < 16; ++q) tot += redF[q][tid];
      out[(size_t)Sd * HHBc + tid] = __logf(tot + EPSF) + MbS[tid];
    }
  }
}

extern "C" void kernel_launch(void* const* d_in, const int* in_sizes, int n_in,
                              void* d_out, int out_size, void* d_ws, size_t ws_size,
                              hipStream_t stream) {
  const int* ids = (const int*)d_in[0];
  const float* alpha = (const float*)d_in[1];
  const float* beta = (const float*)d_in[2];
  const float* gamma = (const float*)d_in[3];
  float* out = (float*)d_out;
  unsigned* mslot = (unsigned*)d_ws;               // [8][128][64] u32 = 256 KB
  unsigned* fpart = mslot + 8 * SLOTW;             // [128][64] u32 = 32 KB

  // Re-arm all M/final gates every launch (graph node, re-runs each replay).
  hipMemsetAsync(mslot, 0, (8 * SLOTW + SLOTW) * sizeof(unsigned), stream);
  hipLaunchKernelGGL(sohmm_persistent, dim3(NBLK), dim3(NTHR), 0, stream,
                     ids, alpha, beta, gamma, out, mslot, fpart);
}